// Round 13
// baseline (3990.108 us; speedup 1.0000x reference)
//
#include <hip/hip_runtime.h>
#include <hip/hip_bf16.h>

// SpatialLSTM: B=64, T=2048, D=128, H=256 (4H=1024)
// R14 = R12 with the publish path changed to test the store-drain hypothesis:
//  - publish via global_atomic_swap (RMW executes AT the LLC -> packet visible
//    after one-way flight; a plain agent store can linger in CU write path)
//  - per-lane packets {u32 ctr, f32 h}: all 64 lanes of wave0 publish their
//    own h (deletes 2 __shfl from the pre-store critical path); 64 pkt/slot.
//  - poll waves use all 64 lanes (1 packet/lane).
// Everything else identical to R12 (parity double-buffer, lgkm-only barriers,
// poll-wave partials, fused phase A).
#define BB 64
#define TT 2048
#define DD 128
#define HH 256
#define G4 1024
#define TC 16

typedef _Float16 half2_t __attribute__((ext_vector_type(2)));

#if __has_builtin(__builtin_amdgcn_fdot2)
#define FDOT2(a, b, c) __builtin_amdgcn_fdot2((a), (b), (c), false)
#else
__device__ __forceinline__ float FDOT2(half2_t a, half2_t b, float c) {
    return c + (float)a[0] * (float)b[0] + (float)a[1] * (float)b[1];
}
#endif

__device__ __forceinline__ half2_t u2h(unsigned int u) {
    union { unsigned int u; half2_t h; } x; x.u = u; return x.h;
}
__device__ __forceinline__ unsigned int pkf16(float a, float b) {
    union { _Float16 h[2]; unsigned int u; } x;
    x.h[0] = (_Float16)a; x.h[1] = (_Float16)b; return x.u;
}
__device__ __forceinline__ unsigned short f16b(float a) {
    union { _Float16 h; unsigned short u; } x; x.h = (_Float16)a; return x.u;
}
__device__ __forceinline__ float sigf(float x) {
    return 1.0f / (1.0f + __expf(-x));
}
__device__ __forceinline__ float tanh_fast(float x) {
    return 1.0f - 2.0f / (__expf(2.0f * x) + 1.0f);
}
// LDS-ordering-only barrier (no vmcnt store-ack drain; peers poll the LLC)
__device__ __forceinline__ void bar_lgkm() {
    asm volatile("s_waitcnt lgkmcnt(0)\n\ts_barrier" ::: "memory");
}
__device__ __forceinline__ void wait_lgkm() {
    asm volatile("s_waitcnt lgkmcnt(0)" ::: "memory");
}

// ---- zero the packet mailbox (counters must start < 1 every launch) ----
__global__ void zero_hglob(unsigned long long* hglob) {
    hglob[blockIdx.x * 256 + threadIdx.x] = 0ull;
}

// ---- pack slice-columns: src f32 [K][1024] -> dst f16 [8 slices][128 c][K]
// local col c of slice g <-> global gate col (c>>5)*256 + g*32 + (c&31)
__global__ void __launch_bounds__(128)
pack_slices(const float* __restrict__ src, unsigned short* __restrict__ dst, int K)
{
    const int g = blockIdx.x, kb = blockIdx.y, c = threadIdx.x;
    const int gc = ((c >> 5) << 8) + (g << 5) + (c & 31);
    unsigned int* d32 = (unsigned int*)dst;
    const int dbase = ((g << 7) + c) * K + kb * 64;     // half index, even
    for (int kk = 0; kk < 64; kk += 2) {
        const float a = src[(size_t)(kb * 64 + kk) * G4 + gc];
        const float b = src[(size_t)(kb * 64 + kk + 1) * G4 + gc];
        d32[(dbase + kk) >> 1] = pkf16(a, b);
    }
}

// ============================ R14 main kernel ===============================
// grid 256 x 512: pair = blk&31 (2 batches), g = blk>>5 (slice of 32 h-cols)
extern "C" __global__ void __launch_bounds__(512, 1)
lstm_swap(const float* __restrict__ X, const unsigned short* __restrict__ Upack,
          const unsigned short* __restrict__ Wpack, const float* __restrict__ bias,
          const float* __restrict__ h0, const float* __restrict__ c0,
          unsigned long long* __restrict__ hglob, float* __restrict__ out)
{
    __shared__ __align__(16) uint4 Ulds4[128 * 32];      // 64 KB, swizzled
    __shared__ __align__(16) uint4 Wlds4[128 * 16];      // 32 KB, swizzled
    __shared__ float xw[2][TC][128];                     // 16 KB
    __shared__ __align__(16) unsigned short Xs[2 * TC * DD]; // 8 KB (f16)
    __shared__ float gvp[2][2][8][128];                  // 16 KB partials (parity)
    __shared__ __align__(16) unsigned short hst0[8][32]; // 512 B: peer h (b0)
    __shared__ __align__(16) unsigned short hst1[8][32]; // 512 B: peer h (b1)
    // total ~137 KB -> 1 block/CU, 8 waves

    const int pair = blockIdx.x & 31;
    const int g = blockIdx.x >> 5;
    const int b0 = pair * 2;
    const int tid = threadIdx.x;
    const int wave = tid >> 6, lane = tid & 63;
    const int c = tid & 127, s = tid >> 7;               // xw-GEMM mapping

    // ---- stage U-slice (swizzle granule gr^(c&31)) and W-slice (gr^(c&15)) --
    {
        const uint4* Usrc = (const uint4*)(Upack + (size_t)g * 32768);
        #pragma unroll
        for (int i = 0; i < 8; ++i) {
            const int idx = i * 512 + tid;               // cc*32 + gr
            const int cc = idx >> 5, gr = idx & 31;
            Ulds4[cc * 32 + (gr ^ (cc & 31))] = Usrc[idx];
        }
        const uint4* Wsrc = (const uint4*)(Wpack + (size_t)g * 16384);
        #pragma unroll
        for (int i = 0; i < 4; ++i) {
            const int idx = i * 512 + tid;               // cc*16 + gr
            const int cc = idx >> 4, gr = idx & 15;
            Wlds4[cc * 16 + (gr ^ (cc & 15))] = Wsrc[idx];
        }
    }
    float c_reg = 0.0f, h_last = 0.0f;
    if (wave == 0) {
        const int p = lane >> 5, j = lane & 31;
        c_reg = c0[(size_t)(b0 + p) * HH + (g << 5) + j];
        h_last = h0[(size_t)(b0 + p) * HH + (g << 5) + j];
    }
    const float bc = bias[((c >> 5) << 8) + (g << 5) + (c & 31)];

    // ---- prologue: gvp[0] <- U.h(0) partials; wave w covers slice (g+w)&7 --
    {
        const int pg = (g + wave) & 7;
        if (lane < 32) {
            hst0[wave][lane] = f16b(h0[(size_t)b0 * HH + (pg << 5) + lane]);
            hst1[wave][lane] = f16b(h0[(size_t)(b0 + 1) * HH + (pg << 5) + lane]);
        }
        wait_lgkm();
        const int c0l = lane, c1l = lane + 64;
        float a00 = 0.f, a01 = 0.f, a10 = 0.f, a11 = 0.f;
        #pragma unroll
        for (int ks = 0; ks < 4; ++ks) {
            const int k8 = (pg << 2) + ks;
            const uint4 u0 = Ulds4[c0l * 32 + (k8 ^ (c0l & 31))];
            const uint4 u1 = Ulds4[c1l * 32 + (k8 ^ (c1l & 31))];
            const uint4 hv0 = *(const uint4*)((const char*)&hst0[wave][0] + (ks << 4));
            const uint4 hv1 = *(const uint4*)((const char*)&hst1[wave][0] + (ks << 4));
            a00 = FDOT2(u2h(u0.x), u2h(hv0.x), a00); a01 = FDOT2(u2h(u0.x), u2h(hv1.x), a01);
            a10 = FDOT2(u2h(u1.x), u2h(hv0.x), a10); a11 = FDOT2(u2h(u1.x), u2h(hv1.x), a11);
            a00 = FDOT2(u2h(u0.y), u2h(hv0.y), a00); a01 = FDOT2(u2h(u0.y), u2h(hv1.y), a01);
            a10 = FDOT2(u2h(u1.y), u2h(hv0.y), a10); a11 = FDOT2(u2h(u1.y), u2h(hv1.y), a11);
            a00 = FDOT2(u2h(u0.z), u2h(hv0.z), a00); a01 = FDOT2(u2h(u0.z), u2h(hv1.z), a01);
            a10 = FDOT2(u2h(u1.z), u2h(hv0.z), a10); a11 = FDOT2(u2h(u1.z), u2h(hv1.z), a11);
            a00 = FDOT2(u2h(u0.w), u2h(hv0.w), a00); a01 = FDOT2(u2h(u0.w), u2h(hv1.w), a01);
            a10 = FDOT2(u2h(u1.w), u2h(hv0.w), a10); a11 = FDOT2(u2h(u1.w), u2h(hv1.w), a11);
        }
        gvp[0][0][wave][c0l] = a00;  gvp[0][1][wave][c0l] = a01;
        gvp[0][0][wave][c1l] = a10;  gvp[0][1][wave][c1l] = a11;
    }
    __syncthreads();

    const size_t obase0 = (size_t)b0 * TT * HH + (g << 5);
    const size_t obase1 = (size_t)(b0 + 1) * TT * HH + (g << 5);
    const int slotbase = ((pair << 3) + g) << 1;          // *64 packets

    for (int chunk = 0; chunk < TT / TC; ++chunk) {
        const int t0 = chunk * TC;

        // ---- stage X chunk for 2 batches (f32 -> f16 pairs) ----
        #pragma unroll
        for (int r = 0; r < 2; ++r) {
            const float4 xv = ((const float4*)(X + ((size_t)(b0 + r) * TT + t0) * DD))[tid];
            ((uint2*)Xs)[r * 512 + tid] = make_uint2(pkf16(xv.x, xv.y), pkf16(xv.z, xv.w));
        }
        bar_lgkm();

        // ---- xw[p][t][c] = X@Wslice + bias; thread (c,s): p=s>>1, th=s&1 ----
        {
            const int p = s >> 1, th = s & 1;
            float acc[8];
            #pragma unroll
            for (int t = 0; t < 8; ++t) acc[t] = bc;
            #pragma unroll
            for (int k8 = 0; k8 < 16; ++k8) {
                const uint4 w4 = Wlds4[c * 16 + (k8 ^ (c & 15))];
                #pragma unroll
                for (int t = 0; t < 8; ++t) {
                    const uint4 xg = *(const uint4*)((const char*)Xs +
                                     ((p * 16 + th * 8 + t) << 8) + (k8 << 4));
                    acc[t] = FDOT2(u2h(xg.x), u2h(w4.x), acc[t]);
                    acc[t] = FDOT2(u2h(xg.y), u2h(w4.y), acc[t]);
                    acc[t] = FDOT2(u2h(xg.z), u2h(w4.z), acc[t]);
                    acc[t] = FDOT2(u2h(xg.w), u2h(w4.w), acc[t]);
                }
            }
            #pragma unroll
            for (int t = 0; t < 8; ++t) xw[p][th * 8 + t][c] = acc[t];
        }
        bar_lgkm();

        // ---- TC recurrent steps, single slot each ----
        for (int tt2 = 0; tt2 < TC; ++tt2) {
            const int it = t0 + tt2;
            const int cur = it & 1, nxt = cur ^ 1;
            const int par = (it + 1) & 1;

            if (wave == 0) {
                // gates from gvp[cur] + xw -> h(it+1); swap-publish; own partial
                const int p = lane >> 5, j = lane & 31;
                const float* xr = &xw[p][tt2][0];
                float gi = xr[j], gf = xr[32 + j], gg = xr[64 + j], go = xr[96 + j];
                #pragma unroll
                for (int q = 0; q < 8; ++q) {
                    const float* gq = &gvp[cur][p][q][0];
                    gi += gq[j]; gf += gq[32 + j]; gg += gq[64 + j]; go += gq[96 + j];
                }
                const float it_g = sigf(gi), ft = sigf(gf);
                const float gt = tanh_fast(gg), ot = sigf(go);
                c_reg = fmaf(ft, c_reg, it_g * gt);
                const float hn = ot * tanh_fast(c_reg);
                h_last = hn;
                if (it < TT - 1) {
                    // per-lane packet: {u32 ctr, f32 h}; atomic swap executes
                    // at the LLC -> visible after one-way flight, no WC linger
                    const unsigned long long pkt =
                        ((unsigned long long)(unsigned)(it + 1) << 32) |
                        (unsigned long long)__float_as_uint(hn);
                    (void)__hip_atomic_exchange(
                        &hglob[(size_t)(slotbase + par) * 64 + lane], pkt,
                        __ATOMIC_RELAXED, __HIP_MEMORY_SCOPE_AGENT);
                    if (p == 0) hst0[0][j] = f16b(hn);
                    else        hst1[0][j] = f16b(hn);
                }
                out[(p ? obase1 : obase0) + (size_t)it * HH + j] = hn;
                if (it < TT - 1) {
                    wait_lgkm();
                    const int c0l = lane, c1l = lane + 64;
                    float a00 = 0.f, a01 = 0.f, a10 = 0.f, a11 = 0.f;
                    #pragma unroll
                    for (int ks = 0; ks < 4; ++ks) {
                        const int k8 = (g << 2) + ks;
                        const uint4 u0 = Ulds4[c0l * 32 + (k8 ^ (c0l & 31))];
                        const uint4 u1 = Ulds4[c1l * 32 + (k8 ^ (c1l & 31))];
                        const uint4 hv0 = *(const uint4*)((const char*)&hst0[0][0] + (ks << 4));
                        const uint4 hv1 = *(const uint4*)((const char*)&hst1[0][0] + (ks << 4));
                        a00 = FDOT2(u2h(u0.x), u2h(hv0.x), a00); a01 = FDOT2(u2h(u0.x), u2h(hv1.x), a01);
                        a10 = FDOT2(u2h(u1.x), u2h(hv0.x), a10); a11 = FDOT2(u2h(u1.x), u2h(hv1.x), a11);
                        a00 = FDOT2(u2h(u0.y), u2h(hv0.y), a00); a01 = FDOT2(u2h(u0.y), u2h(hv1.y), a01);
                        a10 = FDOT2(u2h(u1.y), u2h(hv0.y), a10); a11 = FDOT2(u2h(u1.y), u2h(hv1.y), a11);
                        a00 = FDOT2(u2h(u0.z), u2h(hv0.z), a00); a01 = FDOT2(u2h(u0.z), u2h(hv1.z), a01);
                        a10 = FDOT2(u2h(u1.z), u2h(hv0.z), a10); a11 = FDOT2(u2h(u1.z), u2h(hv1.z), a11);
                        a00 = FDOT2(u2h(u0.w), u2h(hv0.w), a00); a01 = FDOT2(u2h(u0.w), u2h(hv1.w), a01);
                        a10 = FDOT2(u2h(u1.w), u2h(hv0.w), a10); a11 = FDOT2(u2h(u1.w), u2h(hv1.w), a11);
                    }
                    gvp[nxt][0][0][c0l] = a00;  gvp[nxt][1][0][c0l] = a01;
                    gvp[nxt][0][0][c1l] = a10;  gvp[nxt][1][0][c1l] = a11;
                }
            } else if (it < TT - 1) {
                // poll peer pg's per-lane packet; partial on arrival
                const int pg = (g + wave) & 7;
                const unsigned long long* q =
                    &hglob[(size_t)((((pair << 3) + pg) << 1) + par) * 64 + lane];
                unsigned long long v; int spins = 0;
                do {
                    v = __hip_atomic_load(q, __ATOMIC_RELAXED, __HIP_MEMORY_SCOPE_AGENT);
                    if (++spins > (1 << 20)) break;      // anti-hang: fail fast
                } while ((unsigned)(v >> 32) != (unsigned)(it + 1));
                const unsigned short hf = f16b(__uint_as_float((unsigned)v));
                if (lane < 32) hst0[wave][lane] = hf;
                else           hst1[wave][lane - 32] = hf;
                wait_lgkm();
                const int c0l = lane, c1l = lane + 64;
                float a00 = 0.f, a01 = 0.f, a10 = 0.f, a11 = 0.f;
                #pragma unroll
                for (int ks = 0; ks < 4; ++ks) {
                    const int k8 = (pg << 2) + ks;
                    const uint4 u0 = Ulds4[c0l * 32 + (k8 ^ (c0l & 31))];
                    const uint4 u1 = Ulds4[c1l * 32 + (k8 ^ (c1l & 31))];
                    const uint4 hv0 = *(const uint4*)((const char*)&hst0[wave][0] + (ks << 4));
                    const uint4 hv1 = *(const uint4*)((const char*)&hst1[wave][0] + (ks << 4));
                    a00 = FDOT2(u2h(u0.x), u2h(hv0.x), a00); a01 = FDOT2(u2h(u0.x), u2h(hv1.x), a01);
                    a10 = FDOT2(u2h(u1.x), u2h(hv0.x), a10); a11 = FDOT2(u2h(u1.x), u2h(hv1.x), a11);
                    a00 = FDOT2(u2h(u0.y), u2h(hv0.y), a00); a01 = FDOT2(u2h(u0.y), u2h(hv1.y), a01);
                    a10 = FDOT2(u2h(u1.y), u2h(hv0.y), a10); a11 = FDOT2(u2h(u1.y), u2h(hv1.y), a11);
                    a00 = FDOT2(u2h(u0.z), u2h(hv0.z), a00); a01 = FDOT2(u2h(u0.z), u2h(hv1.z), a01);
                    a10 = FDOT2(u2h(u1.z), u2h(hv0.z), a10); a11 = FDOT2(u2h(u1.z), u2h(hv1.z), a11);
                    a00 = FDOT2(u2h(u0.w), u2h(hv0.w), a00); a01 = FDOT2(u2h(u0.w), u2h(hv1.w), a01);
                    a10 = FDOT2(u2h(u1.w), u2h(hv0.w), a10); a11 = FDOT2(u2h(u1.w), u2h(hv1.w), a11);
                }
                gvp[nxt][0][wave][c0l] = a00;  gvp[nxt][1][wave][c0l] = a01;
                gvp[nxt][0][wave][c1l] = a10;  gvp[nxt][1][wave][c1l] = a11;
            }
            bar_lgkm();
        }
    }

    if (wave == 0) {
        const int p = lane >> 5, j = lane & 31;
        const size_t base = (size_t)BB * TT * HH;
        out[base + (size_t)(b0 + p) * HH + (g << 5) + j] = h_last;
        out[base + (size_t)BB * HH + (size_t)(b0 + p) * HH + (g << 5) + j] = c_reg;
    }
}

// ===================== R2 fallback (f32, no workspace) ======================
extern "C" __global__ void __launch_bounds__(512)
lstm_persist(const float* __restrict__ X, const float* __restrict__ W,
             const float* __restrict__ U, const float* __restrict__ bias,
             const float* __restrict__ h0, const float* __restrict__ c0,
             float* __restrict__ out)
{
    __shared__ float xw[TC][G4];
    __shared__ float Xs[TC][DD];
    __shared__ float hsh[HH];
    __shared__ float gv[G4];

    const int b = blockIdx.x;
    const int tid = threadIdx.x;
    const float2* __restrict__ U2 = reinterpret_cast<const float2*>(U);
    const float2* __restrict__ W2 = reinterpret_cast<const float2*>(W);

    float c_reg = 0.0f;
    if (tid < HH) { hsh[tid] = h0[b * HH + tid]; c_reg = c0[b * HH + tid]; }
    const float2 bs = reinterpret_cast<const float2*>(bias)[tid];
    __syncthreads();

    for (int chunk = 0; chunk < TT / TC; ++chunk) {
        const int t0 = chunk * TC;
        {
            const float4* src = reinterpret_cast<const float4*>(X + ((size_t)b * TT + t0) * DD);
            float4* dst = reinterpret_cast<float4*>(&Xs[0][0]);
            for (int i = tid; i < TC * DD / 4; i += 512) dst[i] = src[i];
        }
        __syncthreads();
        float acc0[TC], acc1[TC];
        #pragma unroll
        for (int t = 0; t < TC; ++t) { acc0[t] = bs.x; acc1[t] = bs.y; }
        for (int kk = 0; kk < DD; kk += 4) {
            const float2 w0 = W2[(size_t)(kk + 0) * (G4 / 2) + tid];
            const float2 w1 = W2[(size_t)(kk + 1) * (G4 / 2) + tid];
            const float2 w2 = W2[(size_t)(kk + 2) * (G4 / 2) + tid];
            const float2 w3 = W2[(size_t)(kk + 3) * (G4 / 2) + tid];
            #pragma unroll
            for (int t = 0; t < TC; ++t) {
                const float4 xv = *reinterpret_cast<const float4*>(&Xs[t][kk]);
                acc0[t] = fmaf(xv.x, w0.x, acc0[t]); acc1[t] = fmaf(xv.x, w0.y, acc1[t]);
                acc0[t] = fmaf(xv.y, w1.x, acc0[t]); acc1[t] = fmaf(xv.y, w1.y, acc1[t]);
                acc0[t] = fmaf(xv.z, w2.x, acc0[t]); acc1[t] = fmaf(xv.z, w2.y, acc1[t]);
                acc0[t] = fmaf(xv.w, w3.x, acc0[t]); acc1[t] = fmaf(xv.w, w3.y, acc1[t]);
            }
        }
        #pragma unroll
        for (int t = 0; t < TC; ++t)
            *reinterpret_cast<float2*>(&xw[t][2 * tid]) = make_float2(acc0[t], acc1[t]);
        __syncthreads();

        for (int t = 0; t < TC; ++t) {
            const float2 x2 = *reinterpret_cast<const float2*>(&xw[t][2 * tid]);
            float a0 = x2.x, a1 = x2.y;
            #pragma unroll 4
            for (int k = 0; k < HH; k += 4) {
                const float4 hk = *reinterpret_cast<const float4*>(&hsh[k]);
                const float2 u0 = U2[(size_t)(k + 0) * (G4 / 2) + tid];
                const float2 u1 = U2[(size_t)(k + 1) * (G4 / 2) + tid];
                const float2 u2 = U2[(size_t)(k + 2) * (G4 / 2) + tid];
                const float2 u3 = U2[(size_t)(k + 3) * (G4 / 2) + tid];
                a0 = fmaf(hk.x, u0.x, a0); a1 = fmaf(hk.x, u0.y, a1);
                a0 = fmaf(hk.y, u1.x, a0); a1 = fmaf(hk.y, u1.y, a1);
                a0 = fmaf(hk.z, u2.x, a0); a1 = fmaf(hk.z, u2.y, a1);
                a0 = fmaf(hk.w, u3.x, a0); a1 = fmaf(hk.w, u3.y, a1);
            }
            *reinterpret_cast<float2*>(&gv[2 * tid]) = make_float2(a0, a1);
            __syncthreads();
            if (tid < HH) {
                const float it = sigf(gv[tid]);
                const float ft = sigf(gv[tid + HH]);
                const float gt = tanh_fast(gv[tid + 2 * HH]);
                const float ot = sigf(gv[tid + 3 * HH]);
                c_reg = fmaf(ft, c_reg, it * gt);
                const float hn = ot * tanh_fast(c_reg);
                hsh[tid] = hn;
                out[((size_t)b * TT + (t0 + t)) * HH + tid] = hn;
            }
            __syncthreads();
        }
    }
    if (tid < HH) {
        const size_t base = (size_t)BB * TT * HH;
        out[base + (size_t)b * HH + tid] = hsh[tid];
        out[base + (size_t)BB * HH + (size_t)b * HH + tid] = c_reg;
    }
}

extern "C" void kernel_launch(void* const* d_in, const int* in_sizes, int n_in,
                              void* d_out, int out_size, void* d_ws, size_t ws_size,
                              hipStream_t stream) {
    const float* X    = (const float*)d_in[0];
    const float* W    = (const float*)d_in[1];
    const float* U    = (const float*)d_in[2];
    const float* bias = (const float*)d_in[3];
    const float* h0   = (const float*)d_in[4];
    const float* c0   = (const float*)d_in[5];
    float* out = (float*)d_out;
    (void)in_sizes; (void)n_in; (void)out_size;

    const size_t upk = 512 * 1024;     // Upack f16 [8][128][256]
    const size_t wpk = 256 * 1024;     // Wpack f16 [8][128][128]
    const size_t mbx = 256 * 1024;     // mailbox u64 [32][8][2][64]

    // --- R14 path: 1 MB workspace ---
    if (ws_size >= upk + wpk + mbx) {
        unsigned short* Upack = (unsigned short*)d_ws;
        unsigned short* Wpack = (unsigned short*)((char*)d_ws + upk);
        unsigned long long* hglob = (unsigned long long*)((char*)d_ws + upk + wpk);
        zero_hglob<<<dim3(128), dim3(256), 0, stream>>>(hglob);
        pack_slices<<<dim3(8, 4), dim3(128), 0, stream>>>(U, Upack, 256);
        pack_slices<<<dim3(8, 2), dim3(128), 0, stream>>>(W, Wpack, 128);
        lstm_swap<<<dim3(256), dim3(512), 0, stream>>>(
            X, Upack, Wpack, bias, h0, c0, hglob, out);
        return;
    }

    // --- R2 fallback: no workspace ---
    lstm_persist<<<dim3(BB), dim3(512), 0, stream>>>(X, W, U, bias, h0, c0, out);
}

// Round 14
// 3520.838 us; speedup vs baseline: 1.1333x; 1.1333x over previous
//
#include <hip/hip_runtime.h>
#include <hip/hip_bf16.h>

// SpatialLSTM: B=64, T=2048, D=128, H=256 (4H=1024)
// R15 = R7 (best measured: 3552us) + s_setprio(1) around wave0's producer
// path (gates->publish sits on the serial critical path while 7 poller waves
// spin-compete for issue slots -- T5's role-diversity regime).
// R7 structure: 8 slices x 32 batch-pairs = 256 blocks; U/W slices
// LDS-resident; fused {u32 ctr, f32 h} packets, parity double-buffered;
// lgkm-only barriers; batch-pipelined slots (publish gets a 1-slot head
// start over its matching poll).
#define BB 64
#define TT 2048
#define DD 128
#define HH 256
#define G4 1024
#define TC 16

typedef _Float16 half2_t __attribute__((ext_vector_type(2)));

#if __has_builtin(__builtin_amdgcn_fdot2)
#define FDOT2(a, b, c) __builtin_amdgcn_fdot2((a), (b), (c), false)
#else
__device__ __forceinline__ float FDOT2(half2_t a, half2_t b, float c) {
    return c + (float)a[0] * (float)b[0] + (float)a[1] * (float)b[1];
}
#endif

__device__ __forceinline__ half2_t u2h(unsigned int u) {
    union { unsigned int u; half2_t h; } x; x.u = u; return x.h;
}
__device__ __forceinline__ unsigned int pkf16(float a, float b) {
    union { _Float16 h[2]; unsigned int u; } x;
    x.h[0] = (_Float16)a; x.h[1] = (_Float16)b; return x.u;
}
__device__ __forceinline__ unsigned short f16b(float a) {
    union { _Float16 h; unsigned short u; } x; x.h = (_Float16)a; return x.u;
}
__device__ __forceinline__ float sigf(float x) {
    return 1.0f / (1.0f + __expf(-x));
}
__device__ __forceinline__ float tanh_fast(float x) {
    return 1.0f - 2.0f / (__expf(2.0f * x) + 1.0f);
}
// LDS-ordering-only barrier (no vmcnt store-ack drain; peers poll the LLC)
__device__ __forceinline__ void bar_lgkm() {
    asm volatile("s_waitcnt lgkmcnt(0)\n\ts_barrier" ::: "memory");
}

// ---- zero the packet mailbox (counters must start < 1 every launch) ----
__global__ void zero_hglob(unsigned long long* hglob) {
    hglob[blockIdx.x * 256 + threadIdx.x] = 0ull;
}

// ---- pack slice-columns: src f32 [K][1024] -> dst f16 [8 slices][128 c][K]
// local col c of slice g <-> global gate col (c>>5)*256 + g*32 + (c&31)
__global__ void __launch_bounds__(128)
pack_slices(const float* __restrict__ src, unsigned short* __restrict__ dst, int K)
{
    const int g = blockIdx.x, kb = blockIdx.y, c = threadIdx.x;
    const int gc = ((c >> 5) << 8) + (g << 5) + (c & 31);
    unsigned int* d32 = (unsigned int*)dst;
    const int dbase = ((g << 7) + c) * K + kb * 64;     // half index, even
    for (int kk = 0; kk < 64; kk += 2) {
        const float a = src[(size_t)(kb * 64 + kk) * G4 + gc];
        const float b = src[(size_t)(kb * 64 + kk + 1) * G4 + gc];
        d32[(dbase + kk) >> 1] = pkf16(a, b);
    }
}

// ============================ main kernel ===================================
// grid 256: pair = blk&31 (2 batches), g = blk>>5 (slice of 32 h-cols)
extern "C" __global__ void __launch_bounds__(512, 2)
lstm_pipe(const float* __restrict__ X, const unsigned short* __restrict__ Upack,
          const unsigned short* __restrict__ Wpack, const float* __restrict__ bias,
          const float* __restrict__ h0, const float* __restrict__ c0,
          unsigned long long* __restrict__ hglob, float* __restrict__ out)
{
    __shared__ __align__(16) uint4 Ulds4[128 * 32];      // 64 KB, swizzled
    __shared__ __align__(16) uint4 Wlds4[128 * 16];      // 32 KB, swizzled
    __shared__ float xw[2][TC][128];                     // 16 KB
    __shared__ __align__(16) unsigned short Xs[2 * TC * DD]; // 8 KB (f16)
    __shared__ float gvp[4][128];                        // 2 KB partials
    __shared__ __align__(16) unsigned short hsh[2 * HH]; // 1 KB

    const int pair = blockIdx.x & 31;
    const int g = blockIdx.x >> 5;
    const int b0 = pair * 2;
    const int tid = threadIdx.x;
    const int wave = tid >> 6, lane = tid & 63;
    const int c = tid & 127, s = tid >> 7;               // local col, k-quarter

    {
        const uint4* Usrc = (const uint4*)(Upack + (size_t)g * 32768);
        #pragma unroll
        for (int i = 0; i < 8; ++i) {
            const int idx = i * 512 + tid;               // cc*32 + gr
            const int cc = idx >> 5, gr = idx & 31;
            Ulds4[cc * 32 + (gr ^ (cc & 31))] = Usrc[idx];
        }
        const uint4* Wsrc = (const uint4*)(Wpack + (size_t)g * 16384);
        #pragma unroll
        for (int i = 0; i < 4; ++i) {
            const int idx = i * 512 + tid;               // cc*16 + gr
            const int cc = idx >> 4, gr = idx & 15;
            Wlds4[cc * 16 + (gr ^ (cc & 15))] = Wsrc[idx];
        }
    }
    hsh[tid] = f16b(h0[(size_t)(b0 + (tid >> 8)) * HH + (tid & 255)]);
    float c_reg0 = 0.0f, c_reg1 = 0.0f, h_last0 = 0.0f, h_last1 = 0.0f;
    if (wave == 0 && lane < 32) {
        c_reg0 = c0[(size_t)b0 * HH + (g << 5) + lane];
        c_reg1 = c0[(size_t)(b0 + 1) * HH + (g << 5) + lane];
        h_last0 = h0[(size_t)b0 * HH + (g << 5) + lane];
        h_last1 = h0[(size_t)(b0 + 1) * HH + (g << 5) + lane];
    }
    const float bc = bias[((c >> 5) << 8) + (g << 5) + (c & 31)];
    __syncthreads();

    const size_t obase0 = (size_t)b0 * TT * HH + (g << 5);
    const size_t obase1 = (size_t)(b0 + 1) * TT * HH + (g << 5);
    const int slotbase = ((pair << 3) + g) << 1;          // *64 packets

    for (int chunk = 0; chunk < TT / TC; ++chunk) {
        const int t0 = chunk * TC;

        // ---- stage X chunk for 2 batches (f32 -> f16 pairs) ----
        #pragma unroll
        for (int r = 0; r < 2; ++r) {
            const float4 xv = ((const float4*)(X + ((size_t)(b0 + r) * TT + t0) * DD))[tid];
            ((uint2*)Xs)[r * 512 + tid] = make_uint2(pkf16(xv.x, xv.y), pkf16(xv.z, xv.w));
        }
        bar_lgkm();

        // ---- xw[p][t][c] = X@Wslice + bias; thread (c,s): p=s>>1, th=s&1 ----
        {
            const int p = s >> 1, th = s & 1;
            float acc[8];
            #pragma unroll
            for (int t = 0; t < 8; ++t) acc[t] = bc;
            #pragma unroll
            for (int k8 = 0; k8 < 16; ++k8) {
                const uint4 w4 = Wlds4[c * 16 + (k8 ^ (c & 15))];
                #pragma unroll
                for (int t = 0; t < 8; ++t) {
                    const uint4 xg = *(const uint4*)((const char*)Xs +
                                     ((p * 16 + th * 8 + t) << 8) + (k8 << 4));
                    acc[t] = FDOT2(u2h(xg.x), u2h(w4.x), acc[t]);
                    acc[t] = FDOT2(u2h(xg.y), u2h(w4.y), acc[t]);
                    acc[t] = FDOT2(u2h(xg.z), u2h(w4.z), acc[t]);
                    acc[t] = FDOT2(u2h(xg.w), u2h(w4.w), acc[t]);
                }
            }
            #pragma unroll
            for (int t = 0; t < 8; ++t) xw[p][th * 8 + t][c] = acc[t];
        }
        bar_lgkm();

        // ---- TC recurrent steps, batch-pipelined slots ----
        for (int tt2 = 0; tt2 < TC; ++tt2) {
            const int tau = t0 + tt2;

            // ===== slot1: phase A for b0 (uses hsh[0..255] = h_b0[tau]) =====
            {
                float a = (s == 0) ? xw[0][tt2][c] : 0.0f;
                #pragma unroll
                for (int ii = 0; ii < 8; ++ii) {
                    const uint4 ug = Ulds4[c * 32 + ((s * 8 + ii) ^ (c & 31))];
                    const uint4 hg = *(const uint4*)((const char*)hsh + (s << 7) + (ii << 4));
                    a = FDOT2(u2h(ug.x), u2h(hg.x), a);
                    a = FDOT2(u2h(ug.y), u2h(hg.y), a);
                    a = FDOT2(u2h(ug.z), u2h(hg.z), a);
                    a = FDOT2(u2h(ug.w), u2h(hg.w), a);
                }
                gvp[s][c] = a;
            }
            bar_lgkm();

            // ===== slot2: gates b0 + publish P0(tau+1)  ||  poll P1(tau) ====
            if (wave == 0) {
                __builtin_amdgcn_s_setprio(1);   // producer critical path
                if (lane < 32) {
                    const int j = lane;
                    float gi = 0.f, gf = 0.f, gg = 0.f, go = 0.f;
                    #pragma unroll
                    for (int q = 0; q < 4; ++q) {
                        gi += gvp[q][j];       gf += gvp[q][32 + j];
                        gg += gvp[q][64 + j];  go += gvp[q][96 + j];
                    }
                    const float it = sigf(gi), ft = sigf(gf);
                    const float gt = tanh_fast(gg), ot = sigf(go);
                    c_reg0 = fmaf(ft, c_reg0, it * gt);
                    const float hn = ot * tanh_fast(c_reg0);
                    h_last0 = hn;
                    const unsigned long long pkt =
                        ((unsigned long long)(unsigned)(tau + 1) << 32) |
                        (unsigned long long)__float_as_uint(hn);
                    __hip_atomic_store(&hglob[(size_t)(slotbase + ((tau + 1) & 1)) * 64 + j],
                                       pkt, __ATOMIC_RELAXED, __HIP_MEMORY_SCOPE_AGENT);
                    out[obase0 + (size_t)tau * HH + j] = hn;
                    hsh[(g << 5) + j] = f16b(hn);
                }
                __builtin_amdgcn_s_setprio(0);
            } else if (tau >= 1 && lane < 32) {
                const int pg = (g + wave) & 7;
                const unsigned long long* q =
                    &hglob[(size_t)((((pair << 3) + pg) << 1) + (tau & 1)) * 64 + 32 + lane];
                unsigned long long v; int spins = 0;
                do {
                    v = __hip_atomic_load(q, __ATOMIC_RELAXED, __HIP_MEMORY_SCOPE_AGENT);
                    if (++spins > (1 << 20)) break;      // anti-hang
                } while ((unsigned)(v >> 32) != (unsigned)tau);
                hsh[256 + (pg << 5) + lane] = f16b(__uint_as_float((unsigned)v));
            }
            bar_lgkm();

            // ===== slot3: phase A for b1 (uses hsh[256..511] = h_b1[tau]) ===
            {
                float a = (s == 0) ? xw[1][tt2][c] : 0.0f;
                #pragma unroll
                for (int ii = 0; ii < 8; ++ii) {
                    const uint4 ug = Ulds4[c * 32 + ((s * 8 + ii) ^ (c & 31))];
                    const uint4 hg = *(const uint4*)((const char*)hsh + 512 + (s << 7) + (ii << 4));
                    a = FDOT2(u2h(ug.x), u2h(hg.x), a);
                    a = FDOT2(u2h(ug.y), u2h(hg.y), a);
                    a = FDOT2(u2h(ug.z), u2h(hg.z), a);
                    a = FDOT2(u2h(ug.w), u2h(hg.w), a);
                }
                gvp[s][c] = a;
            }
            bar_lgkm();

            // ===== slot4: gates b1 + publish P1(tau+1)  ||  poll P0(tau+1) ==
            if (wave == 0) {
                __builtin_amdgcn_s_setprio(1);   // producer critical path
                if (lane < 32) {
                    const int j = lane;
                    float gi = 0.f, gf = 0.f, gg = 0.f, go = 0.f;
                    #pragma unroll
                    for (int q = 0; q < 4; ++q) {
                        gi += gvp[q][j];       gf += gvp[q][32 + j];
                        gg += gvp[q][64 + j];  go += gvp[q][96 + j];
                    }
                    const float it = sigf(gi), ft = sigf(gf);
                    const float gt = tanh_fast(gg), ot = sigf(go);
                    c_reg1 = fmaf(ft, c_reg1, it * gt);
                    const float hn = ot * tanh_fast(c_reg1);
                    h_last1 = hn;
                    const unsigned long long pkt =
                        ((unsigned long long)(unsigned)(tau + 1) << 32) |
                        (unsigned long long)__float_as_uint(hn);
                    __hip_atomic_store(&hglob[(size_t)(slotbase + ((tau + 1) & 1)) * 64 + 32 + j],
                                       pkt, __ATOMIC_RELAXED, __HIP_MEMORY_SCOPE_AGENT);
                    out[obase1 + (size_t)tau * HH + j] = hn;
                    hsh[256 + (g << 5) + j] = f16b(hn);
                }
                __builtin_amdgcn_s_setprio(0);
            } else if (tau < TT - 1 && lane < 32) {
                const int pg = (g + wave) & 7;
                const unsigned long long* q =
                    &hglob[(size_t)((((pair << 3) + pg) << 1) + ((tau + 1) & 1)) * 64 + lane];
                unsigned long long v; int spins = 0;
                do {
                    v = __hip_atomic_load(q, __ATOMIC_RELAXED, __HIP_MEMORY_SCOPE_AGENT);
                    if (++spins > (1 << 20)) break;      // anti-hang
                } while ((unsigned)(v >> 32) != (unsigned)(tau + 1));
                hsh[(pg << 5) + lane] = f16b(__uint_as_float((unsigned)v));
            }
            bar_lgkm();
        }
    }

    if (wave == 0 && lane < 32) {
        const size_t base = (size_t)BB * TT * HH;
        out[base + (size_t)b0 * HH + (g << 5) + lane] = h_last0;
        out[base + (size_t)(b0 + 1) * HH + (g << 5) + lane] = h_last1;
        out[base + (size_t)BB * HH + (size_t)b0 * HH + (g << 5) + lane] = c_reg0;
        out[base + (size_t)BB * HH + (size_t)(b0 + 1) * HH + (g << 5) + lane] = c_reg1;
    }
}

// ===================== R2 fallback (f32, no workspace) ======================
extern "C" __global__ void __launch_bounds__(512)
lstm_persist(const float* __restrict__ X, const float* __restrict__ W,
             const float* __restrict__ U, const float* __restrict__ bias,
             const float* __restrict__ h0, const float* __restrict__ c0,
             float* __restrict__ out)
{
    __shared__ float xw[TC][G4];
    __shared__ float Xs[TC][DD];
    __shared__ float hsh[HH];
    __shared__ float gv[G4];

    const int b = blockIdx.x;
    const int tid = threadIdx.x;
    const float2* __restrict__ U2 = reinterpret_cast<const float2*>(U);
    const float2* __restrict__ W2 = reinterpret_cast<const float2*>(W);

    float c_reg = 0.0f;
    if (tid < HH) { hsh[tid] = h0[b * HH + tid]; c_reg = c0[b * HH + tid]; }
    const float2 bs = reinterpret_cast<const float2*>(bias)[tid];
    __syncthreads();

    for (int chunk = 0; chunk < TT / TC; ++chunk) {
        const int t0 = chunk * TC;
        {
            const float4* src = reinterpret_cast<const float4*>(X + ((size_t)b * TT + t0) * DD);
            float4* dst = reinterpret_cast<float4*>(&Xs[0][0]);
            for (int i = tid; i < TC * DD / 4; i += 512) dst[i] = src[i];
        }
        __syncthreads();
        float acc0[TC], acc1[TC];
        #pragma unroll
        for (int t = 0; t < TC; ++t) { acc0[t] = bs.x; acc1[t] = bs.y; }
        for (int kk = 0; kk < DD; kk += 4) {
            const float2 w0 = W2[(size_t)(kk + 0) * (G4 / 2) + tid];
            const float2 w1 = W2[(size_t)(kk + 1) * (G4 / 2) + tid];
            const float2 w2 = W2[(size_t)(kk + 2) * (G4 / 2) + tid];
            const float2 w3 = W2[(size_t)(kk + 3) * (G4 / 2) + tid];
            #pragma unroll
            for (int t = 0; t < TC; ++t) {
                const float4 xv = *reinterpret_cast<const float4*>(&Xs[t][kk]);
                acc0[t] = fmaf(xv.x, w0.x, acc0[t]); acc1[t] = fmaf(xv.x, w0.y, acc1[t]);
                acc0[t] = fmaf(xv.y, w1.x, acc0[t]); acc1[t] = fmaf(xv.y, w1.y, acc1[t]);
                acc0[t] = fmaf(xv.z, w2.x, acc0[t]); acc1[t] = fmaf(xv.z, w2.y, acc1[t]);
                acc0[t] = fmaf(xv.w, w3.x, acc0[t]); acc1[t] = fmaf(xv.w, w3.y, acc1[t]);
            }
        }
        #pragma unroll
        for (int t = 0; t < TC; ++t)
            *reinterpret_cast<float2*>(&xw[t][2 * tid]) = make_float2(acc0[t], acc1[t]);
        __syncthreads();

        for (int t = 0; t < TC; ++t) {
            const float2 x2 = *reinterpret_cast<const float2*>(&xw[t][2 * tid]);
            float a0 = x2.x, a1 = x2.y;
            #pragma unroll 4
            for (int k = 0; k < HH; k += 4) {
                const float4 hk = *reinterpret_cast<const float4*>(&hsh[k]);
                const float2 u0 = U2[(size_t)(k + 0) * (G4 / 2) + tid];
                const float2 u1 = U2[(size_t)(k + 1) * (G4 / 2) + tid];
                const float2 u2 = U2[(size_t)(k + 2) * (G4 / 2) + tid];
                const float2 u3 = U2[(size_t)(k + 3) * (G4 / 2) + tid];
                a0 = fmaf(hk.x, u0.x, a0); a1 = fmaf(hk.x, u0.y, a1);
                a0 = fmaf(hk.y, u1.x, a0); a1 = fmaf(hk.y, u1.y, a1);
                a0 = fmaf(hk.z, u2.x, a0); a1 = fmaf(hk.z, u2.y, a1);
                a0 = fmaf(hk.w, u3.x, a0); a1 = fmaf(hk.w, u3.y, a1);
            }
            *reinterpret_cast<float2*>(&gv[2 * tid]) = make_float2(a0, a1);
            __syncthreads();
            if (tid < HH) {
                const float it = sigf(gv[tid]);
                const float ft = sigf(gv[tid + HH]);
                const float gt = tanh_fast(gv[tid + 2 * HH]);
                const float ot = sigf(gv[tid + 3 * HH]);
                c_reg = fmaf(ft, c_reg, it * gt);
                const float hn = ot * tanh_fast(c_reg);
                hsh[tid] = hn;
                out[((size_t)b * TT + (t0 + t)) * HH + tid] = hn;
            }
            __syncthreads();
        }
    }
    if (tid < HH) {
        const size_t base = (size_t)BB * TT * HH;
        out[base + (size_t)b * HH + tid] = hsh[tid];
        out[base + (size_t)BB * HH + (size_t)b * HH + tid] = c_reg;
    }
}

extern "C" void kernel_launch(void* const* d_in, const int* in_sizes, int n_in,
                              void* d_out, int out_size, void* d_ws, size_t ws_size,
                              hipStream_t stream) {
    const float* X    = (const float*)d_in[0];
    const float* W    = (const float*)d_in[1];
    const float* U    = (const float*)d_in[2];
    const float* bias = (const float*)d_in[3];
    const float* h0   = (const float*)d_in[4];
    const float* c0   = (const float*)d_in[5];
    float* out = (float*)d_out;
    (void)in_sizes; (void)n_in; (void)out_size;

    const size_t upk = 512 * 1024;     // Upack f16 [8][128][256]
    const size_t wpk = 256 * 1024;     // Wpack f16 [8][128][128]
    const size_t mbx = 256 * 1024;     // mailbox u64 [32][8][2][2][32]

    // --- R15 path: 1 MB workspace ---
    if (ws_size >= upk + wpk + mbx) {
        unsigned short* Upack = (unsigned short*)d_ws;
        unsigned short* Wpack = (unsigned short*)((char*)d_ws + upk);
        unsigned long long* hglob = (unsigned long long*)((char*)d_ws + upk + wpk);
        zero_hglob<<<dim3(128), dim3(256), 0, stream>>>(hglob);
        pack_slices<<<dim3(8, 4), dim3(128), 0, stream>>>(U, Upack, 256);
        pack_slices<<<dim3(8, 2), dim3(128), 0, stream>>>(W, Wpack, 128);
        lstm_pipe<<<dim3(256), dim3(512), 0, stream>>>(
            X, Upack, Wpack, bias, h0, c0, hglob, out);
        return;
    }

    // --- R2 fallback: no workspace ---
    lstm_persist<<<dim3(BB), dim3(512), 0, stream>>>(X, W, U, bias, h0, c0, out);
}